// Round 7
// baseline (24036.827 us; speedup 1.0000x reference)
//
#include <hip/hip_runtime.h>
#include <hip/hip_bf16.h>
#include <math.h>

// Problem constants: V=32000, D=256, H=256, L=2, C=2, B=64, T=1024, PAD=0
namespace {
constexpr int Bn = 64;
constexpr int Tn = 1024;
constexpr int Dn = 256;
constexpr int Hn = 256;
}

typedef __attribute__((ext_vector_type(8))) short short8;
typedef __attribute__((ext_vector_type(4))) float f32x4;

template <typename T>
__device__ __forceinline__ float ldf(const T* p, long i);
template <>
__device__ __forceinline__ float ldf<float>(const float* p, long i) { return p[i]; }
template <>
__device__ __forceinline__ float ldf<__hip_bfloat16>(const __hip_bfloat16* p, long i) {
  return __bfloat162float(p[i]);
}

__device__ __forceinline__ float sigmf(float x) { return 1.0f / (1.0f + __expf(-x)); }
__device__ __forceinline__ float tanh_fast(float x) {
  return 1.0f - 2.0f / (__expf(2.0f * x) + 1.0f);
}

// ---------------------------------------------------------------------------
// Dtype detector (validated round 2: flag=1 -> f32 inputs).
// ---------------------------------------------------------------------------
__global__ void k_detect(const unsigned short* __restrict__ e, int* __restrict__ flag) {
  __shared__ int sbuf[256];
  int bad = 0;
  for (int i = threadIdx.x; i < 4096; i += 256) {
    const unsigned short v = e[i];
    const int ex = (v >> 7) & 0xFF;
    bad += (ex >= 137) ? 1 : 0;
  }
  sbuf[threadIdx.x] = bad;
  __syncthreads();
  for (int s = 128; s > 0; s >>= 1) {
    if (threadIdx.x < s) sbuf[threadIdx.x] += sbuf[threadIdx.x + s];
    __syncthreads();
  }
  if (threadIdx.x == 0) flag[0] = (sbuf[0] > 64) ? 1 : 0;
}

__global__ void k_lengths(const int* __restrict__ x, int* __restrict__ len) {
  const int b = blockIdx.x;
  int cnt = 0;
  for (int t = threadIdx.x; t < Tn; t += blockDim.x) cnt += (x[b * Tn + t] != 0) ? 1 : 0;
  __shared__ int sbuf[256];
  sbuf[threadIdx.x] = cnt;
  __syncthreads();
  for (int s = 128; s > 0; s >>= 1) {
    if (threadIdx.x < s) sbuf[threadIdx.x] += sbuf[threadIdx.x + s];
    __syncthreads();
  }
  if (threadIdx.x == 0) len[b] = sbuf[0];
}

// ===========================================================================
// FAST PATH
// ===========================================================================

// biases -> f32 [4][1024] (order: f0,b0,f1,b1).
__global__ void k_prep_small(const void* b0f, const void* b0b, const void* b1f, const void* b1b,
                             const int* __restrict__ flag, float* __restrict__ biasbuf) {
  const int tid = threadIdx.x;
  const bool isf32 = flag[0] != 0;
  for (int idx = tid; idx < 4096; idx += 256) {
    const int j = idx >> 10, col = idx & 1023;
    const void* src = (j == 0) ? b0f : (j == 1) ? b0b : (j == 2) ? b1f : b1b;
    biasbuf[idx] = isf32 ? ((const float*)src)[col]
                         : __bfloat162float(((const __hip_bfloat16*)src)[col]);
  }
}

// Transpose+convert W[(H+XK) x 1024] -> WhT bf16 [1024][256], WxT bf16 [1024][XK].
__global__ void k_prepw(const void* W0, const void* W1, const void* W2, const void* W3,
                        const int* __restrict__ flag, __hip_bfloat16* __restrict__ whT,
                        __hip_bfloat16* __restrict__ wxT0, __hip_bfloat16* __restrict__ wxT1) {
  const int j = blockIdx.z;
  const int rows = (j < 2) ? 512 : 768;
  const int bx = blockIdx.x;
  if (bx * 64 >= rows) return;
  const int by = blockIdx.y;
  const void* W = (j == 0) ? W0 : (j == 1) ? W1 : (j == 2) ? W2 : W3;
  const bool isf32 = flag[0] != 0;
  __shared__ float tile[64][65];
  const int tid = threadIdx.x;
  const int c = tid & 63, r4 = tid >> 6;
#pragma unroll
  for (int rep = 0; rep < 16; ++rep) {
    const int rr = r4 * 16 + rep;
    const size_t idx = (size_t)(bx * 64 + rr) * 1024 + by * 64 + c;
    tile[rr][c] = isf32 ? ((const float*)W)[idx]
                        : __bfloat162float(((const __hip_bfloat16*)W)[idx]);
  }
  __syncthreads();
  const int kk = tid & 63;
#pragma unroll
  for (int rep = 0; rep < 16; ++rep) {
    const int a = r4 * 16 + rep;
    const int n = by * 64 + a;
    const int k = bx * 64 + kk;
    const __hip_bfloat16 v = __float2bfloat16(tile[kk][a]);
    if (k < 256) {
      whT[(size_t)j * (1024 * 256) + (size_t)n * 256 + k] = v;
    } else {
      const int k2 = k - 256;
      if (j < 2)
        wxT0[(size_t)j * (1024 * 256) + (size_t)n * 256 + k2] = v;
      else
        wxT1[(size_t)(j - 2) * (1024 * 512) + (size_t)n * 512 + k2] = v;
    }
  }
}

// ---------------------------------------------------------------------------
// Phased xproj GEMM (unchanged).
// ---------------------------------------------------------------------------
template <int LAYER>
__launch_bounds__(256, 2)
__global__ void k_xproj(const int* __restrict__ x, const void* __restrict__ E,
                        const int* __restrict__ flag, const __hip_bfloat16* __restrict__ seq0,
                        const __hip_bfloat16* __restrict__ WT,  // [2][1024][K]
                        const float* __restrict__ bias,         // [2][1024]
                        float* __restrict__ xp,                 // [2][Tc][64][1024]
                        const int t0f, const int t0b, const int Tc) {
  constexpr int K = (LAYER == 0) ? 256 : 512;
  constexpr int NK = K / 32;
  const int tl = blockIdx.x, by = blockIdx.y, dz = blockIdx.z;
  const int t = (dz ? t0b : t0f) + tl;
  const int tid = threadIdx.x, w = tid >> 6, L = tid & 63, quad = L >> 4, l16 = L & 15;
  const __hip_bfloat16* __restrict__ WTd = WT + (size_t)dz * (1024 * K);
  const float* __restrict__ bsd = bias + dz * 1024;
  float* __restrict__ o = xp + (size_t)(dz * Tc + tl) * (64 * 1024);

  short8 afrag[NK];
  const int bA = w * 16 + l16;
  if constexpr (LAYER == 0) {
    const int tok = x[bA * Tn + t];
    if (flag[0]) {
      const float* __restrict__ er = (const float*)E + (size_t)tok * Dn;
#pragma unroll
      for (int kc = 0; kc < NK; ++kc) {
        short8 a;
#pragma unroll
        for (int jj = 0; jj < 8; ++jj) {
          const __hip_bfloat16 hv = __float2bfloat16(er[kc * 32 + quad * 8 + jj]);
          a[jj] = *(const short*)&hv;
        }
        afrag[kc] = a;
      }
    } else {
      const __hip_bfloat16* __restrict__ er = (const __hip_bfloat16*)E + (size_t)tok * Dn;
#pragma unroll
      for (int kc = 0; kc < NK; ++kc) afrag[kc] = *(const short8*)(er + kc * 32 + quad * 8);
    }
  } else {
    const __hip_bfloat16* __restrict__ ar = seq0 + ((size_t)t * 64 + bA) * 512;
#pragma unroll
    for (int kc = 0; kc < NK; ++kc) afrag[kc] = *(const short8*)(ar + kc * 32 + quad * 8);
  }

  f32x4 acc[4];
#pragma unroll
  for (int nt = 0; nt < 4; ++nt) {
    const float bv = bsd[by * 64 + nt * 16 + l16];
    acc[nt][0] = bv; acc[nt][1] = bv; acc[nt][2] = bv; acc[nt][3] = bv;
  }
#pragma unroll
  for (int kc = 0; kc < NK; ++kc) {
#pragma unroll
    for (int nt = 0; nt < 4; ++nt) {
      const short8 b =
          *(const short8*)(WTd + (size_t)(by * 64 + nt * 16 + l16) * K + kc * 32 + quad * 8);
      acc[nt] = __builtin_amdgcn_mfma_f32_16x16x32_bf16(afrag[kc], b, acc[nt], 0, 0, 0);
    }
  }
#pragma unroll
  for (int nt = 0; nt < 4; ++nt)
#pragma unroll
    for (int r = 0; r < 4; ++r)
      o[(size_t)(w * 16 + quad * 4 + r) * 1024 + by * 64 + nt * 16 + l16] = acc[nt][r];
}

// ---------------------------------------------------------------------------
// Phased recurrent layer, WRITE-THROUGH sync (no fences, no bulk L2 ops).
// 8 blocks: blockIdx.x = d*4+q; block (d,q) owns units [q*64, q*64+64).
// Mailbox: hgs[d][parity][q][64 b][64 u] bf16. Producer publishes its slice
// with relaxed AGENT-scope u16 atomic stores (write-through to L3), drains
// vmcnt, then each WAVE posts its own relaxed flag. Consumers read peers'
// slices with relaxed AGENT-scope u64 atomic loads (always from L3) — no
// threadfence anywhere, so no buffer_wbl2 / buffer_inv per step.
// Flags: [d][Tn][4 q][4 wave][16 u32] (one cacheline per flag), monotone tags.
// ---------------------------------------------------------------------------
template <bool WRITE_SEQ>
__launch_bounds__(256, 1) __global__
void k_lstm_fast(const __hip_bfloat16* __restrict__ WhT,  // [2][1024][256] this layer
                 const float* __restrict__ xproj,          // [2][Tc][64][1024] f32
                 const int* __restrict__ lengths,
                 unsigned* __restrict__ flags,  // [2][Tn][4][4][16] u32
                 __hip_bfloat16* __restrict__ hgs,         // [2][2][4][64][64]
                 float* __restrict__ cstate, float* __restrict__ hstate,  // [2][64][256]
                 __hip_bfloat16* __restrict__ seq0,        // [T][64][512]
                 const int s0, const int Tc) {
  const int d = blockIdx.x >> 2;
  const int q = blockIdx.x & 3;
  const int tid = threadIdx.x;
  const int w = tid >> 6, L = tid & 63, quad = L >> 4, l16 = L & 15;
  const int u = q * 64 + w * 16 + l16;

  __shared__ __hip_bfloat16 h_lds[64][272];  // stride 272 u16: 16B-aligned rows
  for (int idx = tid; idx < 64 * 272; idx += 256) (&h_lds[0][0])[idx] = __float2bfloat16(0.0f);

  const __hip_bfloat16* __restrict__ Wd = WhT + (size_t)d * (1024 * 256);
  short8 wfrag[4][8];
#pragma unroll
  for (int g = 0; g < 4; ++g)
#pragma unroll
    for (int kc = 0; kc < 8; ++kc)
      wfrag[g][kc] = *(const short8*)(Wd + (size_t)(g * 256 + u) * 256 + kc * 32 + quad * 8);

  float c_reg[16], h_reg[16];
  int len_b[16];
#pragma unroll
  for (int mt = 0; mt < 4; ++mt)
#pragma unroll
    for (int r = 0; r < 4; ++r) {
      const int idx = mt * 4 + r;
      const int b = mt * 16 + quad * 4 + r;
      len_b[idx] = lengths[b];
      if (s0 == 0) {
        c_reg[idx] = 0.0f;
        h_reg[idx] = 0.0f;
      } else {
        c_reg[idx] = cstate[((size_t)(d * 64 + b) << 8) + u];
        h_reg[idx] = hstate[((size_t)(d * 64 + b) << 8) + u];
      }
    }
  __syncthreads();
  // seed own slice into LDS (covers both fresh start and phase resume)
#pragma unroll
  for (int mt = 0; mt < 4; ++mt)
#pragma unroll
    for (int r = 0; r < 4; ++r)
      h_lds[mt * 16 + quad * 4 + r][u] = __float2bfloat16(h_reg[mt * 4 + r]);
  __syncthreads();

  for (int sl = 0; sl < Tc; ++sl) {
    const int s = s0 + sl;
    const int t = d ? (Tn - 1 - s) : s;
    const int tl = d ? (Tc - 1 - sl) : sl;

    // 1. C-init from xproj (issued before the wait -> latency hidden)
    f32x4 acc[4][4];
#pragma unroll
    for (int mt = 0; mt < 4; ++mt) {
      const float* __restrict__ xrow =
          xproj + ((size_t)(d * Tc + tl) * 64 + mt * 16 + quad * 4) * 1024 + u;
#pragma unroll
      for (int g = 0; g < 4; ++g)
#pragma unroll
        for (int r = 0; r < 4; ++r) acc[mt][g][r] = xrow[(size_t)r * 1024 + g * 256];
    }

    // 2. wave w polls peer block w's 4 wave-flags (4 lanes in parallel),
    //    then reads peer slice w with write-through u64 loads -> LDS.
    if (s > 0) {
      if (w != q) {
        const size_t fbase = (((size_t)d * Tn + (s - 1)) * 4 + w) * 4;
        if (L < 4) {
          const unsigned* fp = flags + (fbase + L) * 16;
          while (__hip_atomic_load(fp, __ATOMIC_RELAXED, __HIP_MEMORY_SCOPE_AGENT) < (unsigned)s) {
          }
        }
        const unsigned long long* __restrict__ src64 =
            (const unsigned long long*)(hgs + ((((size_t)d * 2 + ((s - 1) & 1)) * 4 + w) << 12));
#pragma unroll
        for (int i = 0; i < 16; ++i) {
          const int idx = i * 64 + L;
          const unsigned long long v =
              __hip_atomic_load(src64 + idx, __ATOMIC_RELAXED, __HIP_MEMORY_SCOPE_AGENT);
          *(unsigned long long*)&h_lds[idx >> 4][w * 64 + (idx & 15) * 4] = v;
        }
      }
      __syncthreads();
    }

    // 3. z += h @ Wh
#pragma unroll
    for (int kc = 0; kc < 8; ++kc) {
#pragma unroll
      for (int mt = 0; mt < 4; ++mt) {
        const short8 a = *(const short8*)&h_lds[mt * 16 + l16][kc * 32 + quad * 8];
#pragma unroll
        for (int g = 0; g < 4; ++g)
          acc[mt][g] =
              __builtin_amdgcn_mfma_f32_16x16x32_bf16(a, wfrag[g][kc], acc[mt][g], 0, 0, 0);
      }
    }

    // 4. gates + state update; publish own mailbox slice (write-through u16)
    unsigned short* __restrict__ dst16 =
        (unsigned short*)(hgs + ((((size_t)d * 2 + (s & 1)) * 4 + q) << 12));
    __hip_bfloat16 hbf[16];
#pragma unroll
    for (int mt = 0; mt < 4; ++mt)
#pragma unroll
      for (int r = 0; r < 4; ++r) {
        const int idx = mt * 4 + r, b = mt * 16 + quad * 4 + r;
        const float fg = sigmf(acc[mt][0][r]);
        const float ig = sigmf(acc[mt][1][r]);
        const float gg = tanh_fast(acc[mt][2][r]);
        const float og = sigmf(acc[mt][3][r]);
        const float cn = fg * c_reg[idx] + ig * gg;
        const float hn = og * tanh_fast(cn);
        if (t < len_b[idx]) {
          c_reg[idx] = cn;
          h_reg[idx] = hn;
        }
        hbf[idx] = __float2bfloat16(h_reg[idx]);
        __hip_atomic_store(dst16 + b * 64 + w * 16 + l16, *(unsigned short*)&hbf[idx],
                           __ATOMIC_RELAXED, __HIP_MEMORY_SCOPE_AGENT);
      }

    // 5. drain this wave's stores (sc-flagged -> visible at L3 when vmcnt=0),
    //    then post this wave's flag. No fence, no barrier on the flag path.
    __builtin_amdgcn_s_waitcnt(0);
    if (L == 0)
      __hip_atomic_store(&flags[((((size_t)d * Tn + s) * 4 + q) * 4 + w) * 16],
                         (unsigned)(s + 1), __ATOMIC_RELAXED, __HIP_MEMORY_SCOPE_AGENT);

    __syncthreads();  // LDS overwrite guard (all MFMA reads of step s done)

    // own h -> LDS for next step; seq0 writes off the critical path
#pragma unroll
    for (int mt = 0; mt < 4; ++mt)
#pragma unroll
      for (int r = 0; r < 4; ++r)
        h_lds[mt * 16 + quad * 4 + r][u] = hbf[mt * 4 + r];

    if (WRITE_SEQ) {
#pragma unroll
      for (int mt = 0; mt < 4; ++mt)
#pragma unroll
        for (int r = 0; r < 4; ++r) {
          const int b = mt * 16 + quad * 4 + r;
          seq0[((size_t)t * 64 + b) * 512 + d * 256 + u] = hbf[mt * 4 + r];
        }
    }
  }

  // save h/c for the next phase (hstate doubles as hfin for the last layer)
#pragma unroll
  for (int mt = 0; mt < 4; ++mt)
#pragma unroll
    for (int r = 0; r < 4; ++r) {
      const int idx = mt * 4 + r, b = mt * 16 + quad * 4 + r;
      cstate[((size_t)(d * 64 + b) << 8) + u] = c_reg[idx];
      hstate[((size_t)(d * 64 + b) << 8) + u] = h_reg[idx];
    }
}

// ===========================================================================
// SLOW FALLBACK PATH (round-2 passing version, used when ws is too small)
// ===========================================================================
template <typename TW, int XK, bool WRITE_SEQ>
__device__ __forceinline__ void lstm_body(const int* __restrict__ x, const TW* __restrict__ E,
                                          const __hip_bfloat16* __restrict__ seq_in,
                                          const TW* __restrict__ W, const TW* __restrict__ bias,
                                          const int len, const int b, const int dir,
                                          __hip_bfloat16* __restrict__ seq_out,
                                          float* __restrict__ hfin) {
  const int j = threadIdx.x;
  __shared__ float h[Hn];
  __shared__ float xb[XK];
  float hj = 0.0f, cj = 0.0f;
  h[j] = 0.0f;
  const float bfj = ldf(bias, j);
  const float bij = ldf(bias, Hn + j);
  const float bgj = ldf(bias, 2 * Hn + j);
  const float boj = ldf(bias, 3 * Hn + j);
  __syncthreads();
  for (int s = 0; s < Tn; ++s) {
    const int t = dir ? (Tn - 1 - s) : s;
    const bool active = (t < len);
    if (active) {
      if constexpr (XK == Dn) {
        const int tok = x[b * Tn + t];
        xb[j] = ldf(E, (long)tok * Dn + j);
      } else {
        const long base = ((long)(b * Tn + t)) * (2 * Hn);
        xb[j] = __bfloat162float(seq_in[base + j]);
        xb[j + Hn] = __bfloat162float(seq_in[base + j + Hn]);
      }
      __syncthreads();
      float af = bfj, ai = bij, ag = bgj, ao = boj;
#pragma unroll 4
      for (int k = 0; k < Hn; ++k) {
        const float hk = h[k];
        const long r = (long)k * (4 * Hn);
        af += hk * ldf(W, r + j);
        ai += hk * ldf(W, r + Hn + j);
        ag += hk * ldf(W, r + 2 * Hn + j);
        ao += hk * ldf(W, r + 3 * Hn + j);
      }
#pragma unroll 4
      for (int k = 0; k < XK; ++k) {
        const float xk = xb[k];
        const long r = (long)(Hn + k) * (4 * Hn);
        af += xk * ldf(W, r + j);
        ai += xk * ldf(W, r + Hn + j);
        ag += xk * ldf(W, r + 2 * Hn + j);
        ao += xk * ldf(W, r + 3 * Hn + j);
      }
      const float fg = 1.0f / (1.0f + expf(-af));
      const float ig = 1.0f / (1.0f + expf(-ai));
      const float gg = tanhf(ag);
      const float og = 1.0f / (1.0f + expf(-ao));
      const float cn = fg * cj + ig * gg;
      const float hn = og * tanhf(cn);
      __syncthreads();
      hj = hn;
      cj = cn;
      h[j] = hn;
      __syncthreads();
    }
    if constexpr (WRITE_SEQ) {
      seq_out[((long)(b * Tn + t)) * (2 * Hn) + dir * Hn + j] = __float2bfloat16(hj);
    }
  }
  if constexpr (!WRITE_SEQ) hfin[(dir * Bn + b) * Hn + j] = hj;
}

template <int XK, bool WRITE_SEQ>
__global__ void k_lstm(const int* __restrict__ x, const void* __restrict__ E,
                       const __hip_bfloat16* __restrict__ seq_in, const void* __restrict__ Wf,
                       const void* __restrict__ bf, const void* __restrict__ Wb,
                       const void* __restrict__ bb, const int* __restrict__ lengths,
                       const int* __restrict__ flag, __hip_bfloat16* __restrict__ seq_out,
                       float* __restrict__ hfin) {
  const int b = blockIdx.x & (Bn - 1);
  const int dir = blockIdx.x >> 6;
  const int len = lengths[b];
  const void* W = dir ? Wb : Wf;
  const void* bias = dir ? bb : bf;
  if (flag[0]) {
    lstm_body<float, XK, WRITE_SEQ>(x, (const float*)E, seq_in, (const float*)W,
                                    (const float*)bias, len, b, dir, seq_out, hfin);
  } else {
    lstm_body<__hip_bfloat16, XK, WRITE_SEQ>(x, (const __hip_bfloat16*)E, seq_in,
                                             (const __hip_bfloat16*)W, (const __hip_bfloat16*)bias,
                                             len, b, dir, seq_out, hfin);
  }
}

// ---------------------------------------------------------------------------
template <typename TW>
__device__ __forceinline__ void fc_body(const float* __restrict__ hfin, const TW* __restrict__ Wfc,
                                        const TW* __restrict__ bfc, TW* __restrict__ out) {
  const int idx = threadIdx.x;
  const int b = idx >> 1;
  const int cc = idx & 1;
  float acc = ldf(bfc, cc);
  for (int k = 0; k < Hn; ++k) acc += hfin[(0 * Bn + b) * Hn + k] * ldf(Wfc, k * 2 + cc);
  for (int k = 0; k < Hn; ++k) acc += hfin[(1 * Bn + b) * Hn + k] * ldf(Wfc, (Hn + k) * 2 + cc);
  if constexpr (sizeof(TW) == 2) {
    out[b * 2 + cc] = __float2bfloat16(acc);
  } else {
    out[b * 2 + cc] = acc;
  }
}

__global__ void k_fc(const float* __restrict__ hfin, const void* __restrict__ Wfc,
                     const void* __restrict__ bfc, const int* __restrict__ flag,
                     void* __restrict__ out) {
  if (flag[0]) {
    fc_body<float>(hfin, (const float*)Wfc, (const float*)bfc, (float*)out);
  } else {
    fc_body<__hip_bfloat16>(hfin, (const __hip_bfloat16*)Wfc, (const __hip_bfloat16*)bfc,
                            (__hip_bfloat16*)out);
  }
}

// ---------------------------------------------------------------------------
extern "C" void kernel_launch(void* const* d_in, const int* in_sizes, int n_in,
                              void* d_out, int out_size, void* d_ws, size_t ws_size,
                              hipStream_t stream) {
  const int* x = (const int*)d_in[0];
  const void* E = d_in[1];
  const void* Wf0 = d_in[2];
  const void* bf0 = d_in[3];
  const void* Wb0 = d_in[4];
  const void* bb0 = d_in[5];
  const void* Wf1 = d_in[6];
  const void* bf1 = d_in[7];
  const void* Wb1 = d_in[8];
  const void* bb1 = d_in[9];
  const void* Wfc = d_in[10];
  const void* bfc = d_in[11];

  char* ws = (char*)d_ws;
  int* flag = (int*)ws;             // @0
  int* lengths = (int*)(ws + 256);

  const size_t MB = 1ull << 20;
  const size_t KB = 1024;

  k_detect<<<1, 256, 0, stream>>>((const unsigned short*)E, flag);
  k_lengths<<<Bn, 256, 0, stream>>>(x, lengths);

  // pick largest xproj chunk (Tc timesteps/dir, Tc*0.5 MB) that fits ws
  int Tc = 0;
  {
    const size_t fixed = 75 * MB + MB;  // weights/state/flags/seq0 + slack
    const int cands[7] = {1024, 512, 256, 128, 64, 32, 16};
    for (int i = 0; i < 7; ++i)
      if (fixed + (size_t)cands[i] * 512 * KB <= ws_size) { Tc = cands[i]; break; }
  }

  if (Tc > 0) {
    float* biasbuf = (float*)(ws + 4096);                    // 16 KB
    __hip_bfloat16* whT = (__hip_bfloat16*)(ws + 1 * MB);    // [4][1024][256] = 2 MB
    __hip_bfloat16* wxT0 = (__hip_bfloat16*)(ws + 3 * MB);   // [2][1024][256] = 1 MB
    __hip_bfloat16* wxT1 = (__hip_bfloat16*)(ws + 4 * MB);   // [2][1024][512] = 2 MB
    __hip_bfloat16* hgs = (__hip_bfloat16*)(ws + 6 * MB);    // [2][2][4][64][64] = 128 KB
    float* cstate0 = (float*)(ws + 6 * MB + 128 * KB);       // 128 KB
    float* hstate0 = (float*)(ws + 6 * MB + 256 * KB);       // 128 KB
    float* cstate1 = (float*)(ws + 6 * MB + 384 * KB);       // 128 KB
    float* hstate1 = (float*)(ws + 6 * MB + 512 * KB);       // 128 KB
    unsigned* flags = (unsigned*)(ws + 7 * MB);              // 2 layers x 2 MB = 4 MB
    __hip_bfloat16* seq0 = (__hip_bfloat16*)(ws + 11 * MB);  // [1024][64][512] = 64 MB
    float* xproj = (float*)(ws + 75 * MB);                   // [2][Tc][64][1024] f32
    unsigned* flags0 = flags;
    unsigned* flags1 = flags + (2 * MB / 4);

    k_prep_small<<<1, 256, 0, stream>>>(bf0, bb0, bf1, bb1, flag, biasbuf);
    k_prepw<<<dim3(12, 16, 4), 256, 0, stream>>>(Wf0, Wb0, Wf1, Wb1, flag, whT, wxT0, wxT1);
    hipMemsetAsync(flags, 0, 4 * MB, stream);

    const int P = Tn / Tc;
    // layer 0
    for (int p = 0; p < P; ++p) {
      const int s0 = p * Tc;
      const int t0f = s0, t0b = Tn - s0 - Tc;
      k_xproj<0><<<dim3(Tc, 16, 2), 256, 0, stream>>>(x, E, flag, nullptr, wxT0, biasbuf, xproj,
                                                      t0f, t0b, Tc);
      k_lstm_fast<true><<<8, 256, 0, stream>>>(whT, xproj, lengths, flags0, hgs, cstate0, hstate0,
                                               seq0, s0, Tc);
    }
    // layer 1
    for (int p = 0; p < P; ++p) {
      const int s0 = p * Tc;
      const int t0f = s0, t0b = Tn - s0 - Tc;
      k_xproj<1><<<dim3(Tc, 16, 2), 256, 0, stream>>>(x, E, flag, seq0, wxT1, biasbuf + 2048,
                                                      xproj, t0f, t0b, Tc);
      k_lstm_fast<false><<<8, 256, 0, stream>>>(whT + 2 * 1024 * 256, xproj, lengths, flags1, hgs,
                                                cstate1, hstate1, nullptr, s0, Tc);
    }
    k_fc<<<1, 128, 0, stream>>>(hstate1, Wfc, bfc, flag, d_out);
  } else {
    // slow fallback (round-2 passing path)
    __hip_bfloat16* seq0 = (__hip_bfloat16*)(ws + 64 * 1024);
    const size_t seq0_bytes = (size_t)Bn * Tn * 2 * Hn * sizeof(__hip_bfloat16);
    float* hfin = (float*)(ws + 64 * 1024 + seq0_bytes);
    k_lstm<Dn, true><<<2 * Bn, 256, 0, stream>>>(x, E, nullptr, Wf0, bf0, Wb0, bb0, lengths, flag,
                                                 seq0, nullptr);
    k_lstm<2 * Hn, false><<<2 * Bn, 256, 0, stream>>>(x, E, seq0, Wf1, bf1, Wb1, bb1, lengths,
                                                      flag, nullptr, hfin);
    k_fc<<<1, 128, 0, stream>>>(hfin, Wfc, bfc, flag, d_out);
  }
}

// Round 8
// 19133.388 us; speedup vs baseline: 1.2563x; 1.2563x over previous
//
#include <hip/hip_runtime.h>
#include <hip/hip_bf16.h>
#include <math.h>

// Problem constants: V=32000, D=256, H=256, L=2, C=2, B=64, T=1024, PAD=0
namespace {
constexpr int Bn = 64;
constexpr int Tn = 1024;
constexpr int Dn = 256;
constexpr int Hn = 256;
}

typedef __attribute__((ext_vector_type(8))) short short8;
typedef __attribute__((ext_vector_type(4))) float f32x4;

template <typename T>
__device__ __forceinline__ float ldf(const T* p, long i);
template <>
__device__ __forceinline__ float ldf<float>(const float* p, long i) { return p[i]; }
template <>
__device__ __forceinline__ float ldf<__hip_bfloat16>(const __hip_bfloat16* p, long i) {
  return __bfloat162float(p[i]);
}

__device__ __forceinline__ float sigmf(float x) { return 1.0f / (1.0f + __expf(-x)); }
__device__ __forceinline__ float tanh_fast(float x) {
  return 1.0f - 2.0f / (__expf(2.0f * x) + 1.0f);
}

// ---------------------------------------------------------------------------
// Dtype detector (validated round 2: flag=1 -> f32 inputs).
// ---------------------------------------------------------------------------
__global__ void k_detect(const unsigned short* __restrict__ e, int* __restrict__ flag) {
  __shared__ int sbuf[256];
  int bad = 0;
  for (int i = threadIdx.x; i < 4096; i += 256) {
    const unsigned short v = e[i];
    const int ex = (v >> 7) & 0xFF;
    bad += (ex >= 137) ? 1 : 0;
  }
  sbuf[threadIdx.x] = bad;
  __syncthreads();
  for (int s = 128; s > 0; s >>= 1) {
    if (threadIdx.x < s) sbuf[threadIdx.x] += sbuf[threadIdx.x + s];
    __syncthreads();
  }
  if (threadIdx.x == 0) flag[0] = (sbuf[0] > 64) ? 1 : 0;
}

__global__ void k_lengths(const int* __restrict__ x, int* __restrict__ len) {
  const int b = blockIdx.x;
  int cnt = 0;
  for (int t = threadIdx.x; t < Tn; t += blockDim.x) cnt += (x[b * Tn + t] != 0) ? 1 : 0;
  __shared__ int sbuf[256];
  sbuf[threadIdx.x] = cnt;
  __syncthreads();
  for (int s = 128; s > 0; s >>= 1) {
    if (threadIdx.x < s) sbuf[threadIdx.x] += sbuf[threadIdx.x + s];
    __syncthreads();
  }
  if (threadIdx.x == 0) len[b] = sbuf[0];
}

// ===========================================================================
// FAST PATH
// ===========================================================================

// biases -> f32 [4][1024] (order: f0,b0,f1,b1).
__global__ void k_prep_small(const void* b0f, const void* b0b, const void* b1f, const void* b1b,
                             const int* __restrict__ flag, float* __restrict__ biasbuf) {
  const int tid = threadIdx.x;
  const bool isf32 = flag[0] != 0;
  for (int idx = tid; idx < 4096; idx += 256) {
    const int j = idx >> 10, col = idx & 1023;
    const void* src = (j == 0) ? b0f : (j == 1) ? b0b : (j == 2) ? b1f : b1b;
    biasbuf[idx] = isf32 ? ((const float*)src)[col]
                         : __bfloat162float(((const __hip_bfloat16*)src)[col]);
  }
}

// Transpose+convert W[(H+XK) x 1024] -> WhT bf16 [1024][256], WxT bf16 [1024][XK].
__global__ void k_prepw(const void* W0, const void* W1, const void* W2, const void* W3,
                        const int* __restrict__ flag, __hip_bfloat16* __restrict__ whT,
                        __hip_bfloat16* __restrict__ wxT0, __hip_bfloat16* __restrict__ wxT1) {
  const int j = blockIdx.z;
  const int rows = (j < 2) ? 512 : 768;
  const int bx = blockIdx.x;
  if (bx * 64 >= rows) return;
  const int by = blockIdx.y;
  const void* W = (j == 0) ? W0 : (j == 1) ? W1 : (j == 2) ? W2 : W3;
  const bool isf32 = flag[0] != 0;
  __shared__ float tile[64][65];
  const int tid = threadIdx.x;
  const int c = tid & 63, r4 = tid >> 6;
#pragma unroll
  for (int rep = 0; rep < 16; ++rep) {
    const int rr = r4 * 16 + rep;
    const size_t idx = (size_t)(bx * 64 + rr) * 1024 + by * 64 + c;
    tile[rr][c] = isf32 ? ((const float*)W)[idx]
                        : __bfloat162float(((const __hip_bfloat16*)W)[idx]);
  }
  __syncthreads();
  const int kk = tid & 63;
#pragma unroll
  for (int rep = 0; rep < 16; ++rep) {
    const int a = r4 * 16 + rep;
    const int n = by * 64 + a;
    const int k = bx * 64 + kk;
    const __hip_bfloat16 v = __float2bfloat16(tile[kk][a]);
    if (k < 256) {
      whT[(size_t)j * (1024 * 256) + (size_t)n * 256 + k] = v;
    } else {
      const int k2 = k - 256;
      if (j < 2)
        wxT0[(size_t)j * (1024 * 256) + (size_t)n * 256 + k2] = v;
      else
        wxT1[(size_t)(j - 2) * (1024 * 512) + (size_t)n * 512 + k2] = v;
    }
  }
}

// ---------------------------------------------------------------------------
// Phased xproj GEMM (unchanged).
// ---------------------------------------------------------------------------
template <int LAYER>
__launch_bounds__(256, 2)
__global__ void k_xproj(const int* __restrict__ x, const void* __restrict__ E,
                        const int* __restrict__ flag, const __hip_bfloat16* __restrict__ seq0,
                        const __hip_bfloat16* __restrict__ WT,  // [2][1024][K]
                        const float* __restrict__ bias,         // [2][1024]
                        float* __restrict__ xp,                 // [2][Tc][64][1024]
                        const int t0f, const int t0b, const int Tc) {
  constexpr int K = (LAYER == 0) ? 256 : 512;
  constexpr int NK = K / 32;
  const int tl = blockIdx.x, by = blockIdx.y, dz = blockIdx.z;
  const int t = (dz ? t0b : t0f) + tl;
  const int tid = threadIdx.x, w = tid >> 6, L = tid & 63, quad = L >> 4, l16 = L & 15;
  const __hip_bfloat16* __restrict__ WTd = WT + (size_t)dz * (1024 * K);
  const float* __restrict__ bsd = bias + dz * 1024;
  float* __restrict__ o = xp + (size_t)(dz * Tc + tl) * (64 * 1024);

  short8 afrag[NK];
  const int bA = w * 16 + l16;
  if constexpr (LAYER == 0) {
    const int tok = x[bA * Tn + t];
    if (flag[0]) {
      const float* __restrict__ er = (const float*)E + (size_t)tok * Dn;
#pragma unroll
      for (int kc = 0; kc < NK; ++kc) {
        short8 a;
#pragma unroll
        for (int jj = 0; jj < 8; ++jj) {
          const __hip_bfloat16 hv = __float2bfloat16(er[kc * 32 + quad * 8 + jj]);
          a[jj] = *(const short*)&hv;
        }
        afrag[kc] = a;
      }
    } else {
      const __hip_bfloat16* __restrict__ er = (const __hip_bfloat16*)E + (size_t)tok * Dn;
#pragma unroll
      for (int kc = 0; kc < NK; ++kc) afrag[kc] = *(const short8*)(er + kc * 32 + quad * 8);
    }
  } else {
    const __hip_bfloat16* __restrict__ ar = seq0 + ((size_t)t * 64 + bA) * 512;
#pragma unroll
    for (int kc = 0; kc < NK; ++kc) afrag[kc] = *(const short8*)(ar + kc * 32 + quad * 8);
  }

  f32x4 acc[4];
#pragma unroll
  for (int nt = 0; nt < 4; ++nt) {
    const float bv = bsd[by * 64 + nt * 16 + l16];
    acc[nt][0] = bv; acc[nt][1] = bv; acc[nt][2] = bv; acc[nt][3] = bv;
  }
#pragma unroll
  for (int kc = 0; kc < NK; ++kc) {
#pragma unroll
    for (int nt = 0; nt < 4; ++nt) {
      const short8 b =
          *(const short8*)(WTd + (size_t)(by * 64 + nt * 16 + l16) * K + kc * 32 + quad * 8);
      acc[nt] = __builtin_amdgcn_mfma_f32_16x16x32_bf16(afrag[kc], b, acc[nt], 0, 0, 0);
    }
  }
#pragma unroll
  for (int nt = 0; nt < 4; ++nt)
#pragma unroll
    for (int r = 0; r < 4; ++r)
      o[(size_t)(w * 16 + quad * 4 + r) * 1024 + by * 64 + nt * 16 + l16] = acc[nt][r];
}

// ---------------------------------------------------------------------------
// Phased recurrent layer, TAGGED-PAYLOAD sync (single-RT exchange).
// 8 blocks: blockIdx.x = d*4+q; block (d,q) owns units [q*64, q*64+64).
// Mailbox word u32 = (tag << 16) | bf16(h), tag = step+1. Producer: 16 relaxed
// agent-scope u32 stores (write-through) — no flag, no fence, no waitcnt.
// Consumer wave w: 32 pipelined u64 atomic loads of peer w's 16 KB slice,
// validates both tags per word, re-loads only stale words. Flag visibility and
// data transfer collapse into ONE L3 round-trip. Separate mailbox per layer
// (no cross-layer tag aliasing); memset at launch (no cross-call staleness);
// 2-slot parity is race-free (publish(s+1) implies all peers consumed s-1).
// ---------------------------------------------------------------------------
template <bool WRITE_SEQ>
__launch_bounds__(256, 1) __global__
void k_lstm_fast(const __hip_bfloat16* __restrict__ WhT,  // [2][1024][256] this layer
                 const float* __restrict__ xproj,          // [2][Tc][64][1024] f32
                 const int* __restrict__ lengths,
                 unsigned* __restrict__ hgs,  // [2 d][2 par][4 q][64 b][64 u] u32
                 float* __restrict__ cstate, float* __restrict__ hstate,  // [2][64][256]
                 __hip_bfloat16* __restrict__ seq0,        // [T][64][512]
                 const int s0, const int Tc) {
  const int d = blockIdx.x >> 2;
  const int q = blockIdx.x & 3;
  const int tid = threadIdx.x;
  const int w = tid >> 6, L = tid & 63, quad = L >> 4, l16 = L & 15;
  const int u = q * 64 + w * 16 + l16;

  __shared__ __hip_bfloat16 h_lds[64][272];  // stride 272 u16: 16B-aligned rows
  for (int idx = tid; idx < 64 * 272; idx += 256) (&h_lds[0][0])[idx] = __float2bfloat16(0.0f);

  const __hip_bfloat16* __restrict__ Wd = WhT + (size_t)d * (1024 * 256);
  short8 wfrag[4][8];
#pragma unroll
  for (int g = 0; g < 4; ++g)
#pragma unroll
    for (int kc = 0; kc < 8; ++kc)
      wfrag[g][kc] = *(const short8*)(Wd + (size_t)(g * 256 + u) * 256 + kc * 32 + quad * 8);

  float c_reg[16], h_reg[16];
  int len_b[16];
#pragma unroll
  for (int mt = 0; mt < 4; ++mt)
#pragma unroll
    for (int r = 0; r < 4; ++r) {
      const int idx = mt * 4 + r;
      const int b = mt * 16 + quad * 4 + r;
      len_b[idx] = lengths[b];
      if (s0 == 0) {
        c_reg[idx] = 0.0f;
        h_reg[idx] = 0.0f;
      } else {
        c_reg[idx] = cstate[((size_t)(d * 64 + b) << 8) + u];
        h_reg[idx] = hstate[((size_t)(d * 64 + b) << 8) + u];
      }
    }
  __syncthreads();
  // seed own slice into LDS (covers both fresh start and phase resume)
#pragma unroll
  for (int mt = 0; mt < 4; ++mt)
#pragma unroll
    for (int r = 0; r < 4; ++r)
      h_lds[mt * 16 + quad * 4 + r][u] = __float2bfloat16(h_reg[mt * 4 + r]);
  __syncthreads();

  for (int sl = 0; sl < Tc; ++sl) {
    const int s = s0 + sl;
    const int t = d ? (Tn - 1 - s) : s;
    const int tl = d ? (Tc - 1 - sl) : sl;

    // 1. C-init from xproj (issued before the exchange -> latency hidden)
    f32x4 acc[4][4];
#pragma unroll
    for (int mt = 0; mt < 4; ++mt) {
      const float* __restrict__ xrow =
          xproj + ((size_t)(d * Tc + tl) * 64 + mt * 16 + quad * 4) * 1024 + u;
#pragma unroll
      for (int g = 0; g < 4; ++g)
#pragma unroll
        for (int r = 0; r < 4; ++r) acc[mt][g][r] = xrow[(size_t)r * 1024 + g * 256];
    }

    // 2. tagged-payload exchange: wave w reads peer w's slice directly,
    //    validating the embedded per-word step tags. One RT in the common case.
    if (s > 0) {
      if (w != q) {
        const unsigned long long* __restrict__ src64 =
            (const unsigned long long*)(hgs + ((((size_t)d * 2 + ((s - 1) & 1)) * 4 + w) << 12));
        const unsigned exp = (unsigned)s;  // producer of step s-1 wrote tag s
        unsigned long long v[32];
        unsigned pend = 0xFFFFFFFFu;
        do {
#pragma unroll
          for (int i = 0; i < 32; ++i)
            if (pend & (1u << i))
              v[i] = __hip_atomic_load(src64 + i * 64 + L, __ATOMIC_RELAXED,
                                       __HIP_MEMORY_SCOPE_AGENT);
#pragma unroll
          for (int i = 0; i < 32; ++i)
            if (pend & (1u << i)) {
              const unsigned lo = (unsigned)v[i], hi = (unsigned)(v[i] >> 32);
              if ((lo >> 16) == exp && (hi >> 16) == exp) pend &= ~(1u << i);
            }
        } while (pend);
#pragma unroll
        for (int i = 0; i < 32; ++i) {
          const int j = i * 64 + L;  // u64 index in [0,2048): b=j>>5, unit pair k=(j&31)
          const unsigned lo = (unsigned)v[i], hi = (unsigned)(v[i] >> 32);
          const unsigned packed = (lo & 0xFFFFu) | (hi << 16);
          *(unsigned*)&h_lds[j >> 5][w * 64 + (j & 31) * 2] = packed;
        }
      }
      __syncthreads();
    }

    // 3. z += h @ Wh
#pragma unroll
    for (int kc = 0; kc < 8; ++kc) {
#pragma unroll
      for (int mt = 0; mt < 4; ++mt) {
        const short8 a = *(const short8*)&h_lds[mt * 16 + l16][kc * 32 + quad * 8];
#pragma unroll
        for (int g = 0; g < 4; ++g)
          acc[mt][g] =
              __builtin_amdgcn_mfma_f32_16x16x32_bf16(a, wfrag[g][kc], acc[mt][g], 0, 0, 0);
      }
    }

    // 4. gates + state update; publish own tagged slice (write-through u32)
    unsigned* __restrict__ dst32 = hgs + ((((size_t)d * 2 + (s & 1)) * 4 + q) << 12);
    const unsigned tag = ((unsigned)(s + 1)) << 16;
    __hip_bfloat16 hbf[16];
#pragma unroll
    for (int mt = 0; mt < 4; ++mt)
#pragma unroll
      for (int r = 0; r < 4; ++r) {
        const int idx = mt * 4 + r, b = mt * 16 + quad * 4 + r;
        const float fg = sigmf(acc[mt][0][r]);
        const float ig = sigmf(acc[mt][1][r]);
        const float gg = tanh_fast(acc[mt][2][r]);
        const float og = sigmf(acc[mt][3][r]);
        const float cn = fg * c_reg[idx] + ig * gg;
        const float hn = og * tanh_fast(cn);
        if (t < len_b[idx]) {
          c_reg[idx] = cn;
          h_reg[idx] = hn;
        }
        hbf[idx] = __float2bfloat16(h_reg[idx]);
        __hip_atomic_store(dst32 + b * 64 + w * 16 + l16,
                           tag | (unsigned)*(unsigned short*)&hbf[idx], __ATOMIC_RELAXED,
                           __HIP_MEMORY_SCOPE_AGENT);
      }

    __syncthreads();  // LDS overwrite guard (all MFMA reads of step s done)

    // own h -> LDS for next step; seq0 writes off the critical path
#pragma unroll
    for (int mt = 0; mt < 4; ++mt)
#pragma unroll
      for (int r = 0; r < 4; ++r)
        h_lds[mt * 16 + quad * 4 + r][u] = hbf[mt * 4 + r];

    if (WRITE_SEQ) {
#pragma unroll
      for (int mt = 0; mt < 4; ++mt)
#pragma unroll
        for (int r = 0; r < 4; ++r) {
          const int b = mt * 16 + quad * 4 + r;
          seq0[((size_t)t * 64 + b) * 512 + d * 256 + u] = hbf[mt * 4 + r];
        }
    }
  }

  // save h/c for the next phase (hstate doubles as hfin for the last layer)
#pragma unroll
  for (int mt = 0; mt < 4; ++mt)
#pragma unroll
    for (int r = 0; r < 4; ++r) {
      const int idx = mt * 4 + r, b = mt * 16 + quad * 4 + r;
      cstate[((size_t)(d * 64 + b) << 8) + u] = c_reg[idx];
      hstate[((size_t)(d * 64 + b) << 8) + u] = h_reg[idx];
    }
}

// ===========================================================================
// SLOW FALLBACK PATH (round-2 passing version, used when ws is too small)
// ===========================================================================
template <typename TW, int XK, bool WRITE_SEQ>
__device__ __forceinline__ void lstm_body(const int* __restrict__ x, const TW* __restrict__ E,
                                          const __hip_bfloat16* __restrict__ seq_in,
                                          const TW* __restrict__ W, const TW* __restrict__ bias,
                                          const int len, const int b, const int dir,
                                          __hip_bfloat16* __restrict__ seq_out,
                                          float* __restrict__ hfin) {
  const int j = threadIdx.x;
  __shared__ float h[Hn];
  __shared__ float xb[XK];
  float hj = 0.0f, cj = 0.0f;
  h[j] = 0.0f;
  const float bfj = ldf(bias, j);
  const float bij = ldf(bias, Hn + j);
  const float bgj = ldf(bias, 2 * Hn + j);
  const float boj = ldf(bias, 3 * Hn + j);
  __syncthreads();
  for (int s = 0; s < Tn; ++s) {
    const int t = dir ? (Tn - 1 - s) : s;
    const bool active = (t < len);
    if (active) {
      if constexpr (XK == Dn) {
        const int tok = x[b * Tn + t];
        xb[j] = ldf(E, (long)tok * Dn + j);
      } else {
        const long base = ((long)(b * Tn + t)) * (2 * Hn);
        xb[j] = __bfloat162float(seq_in[base + j]);
        xb[j + Hn] = __bfloat162float(seq_in[base + j + Hn]);
      }
      __syncthreads();
      float af = bfj, ai = bij, ag = bgj, ao = boj;
#pragma unroll 4
      for (int k = 0; k < Hn; ++k) {
        const float hk = h[k];
        const long r = (long)k * (4 * Hn);
        af += hk * ldf(W, r + j);
        ai += hk * ldf(W, r + Hn + j);
        ag += hk * ldf(W, r + 2 * Hn + j);
        ao += hk * ldf(W, r + 3 * Hn + j);
      }
#pragma unroll 4
      for (int k = 0; k < XK; ++k) {
        const float xk = xb[k];
        const long r = (long)(Hn + k) * (4 * Hn);
        af += xk * ldf(W, r + j);
        ai += xk * ldf(W, r + Hn + j);
        ag += xk * ldf(W, r + 2 * Hn + j);
        ao += xk * ldf(W, r + 3 * Hn + j);
      }
      const float fg = 1.0f / (1.0f + expf(-af));
      const float ig = 1.0f / (1.0f + expf(-ai));
      const float gg = tanhf(ag);
      const float og = 1.0f / (1.0f + expf(-ao));
      const float cn = fg * cj + ig * gg;
      const float hn = og * tanhf(cn);
      __syncthreads();
      hj = hn;
      cj = cn;
      h[j] = hn;
      __syncthreads();
    }
    if constexpr (WRITE_SEQ) {
      seq_out[((long)(b * Tn + t)) * (2 * Hn) + dir * Hn + j] = __float2bfloat16(hj);
    }
  }
  if constexpr (!WRITE_SEQ) hfin[(dir * Bn + b) * Hn + j] = hj;
}

template <int XK, bool WRITE_SEQ>
__global__ void k_lstm(const int* __restrict__ x, const void* __restrict__ E,
                       const __hip_bfloat16* __restrict__ seq_in, const void* __restrict__ Wf,
                       const void* __restrict__ bf, const void* __restrict__ Wb,
                       const void* __restrict__ bb, const int* __restrict__ lengths,
                       const int* __restrict__ flag, __hip_bfloat16* __restrict__ seq_out,
                       float* __restrict__ hfin) {
  const int b = blockIdx.x & (Bn - 1);
  const int dir = blockIdx.x >> 6;
  const int len = lengths[b];
  const void* W = dir ? Wb : Wf;
  const void* bias = dir ? bb : bf;
  if (flag[0]) {
    lstm_body<float, XK, WRITE_SEQ>(x, (const float*)E, seq_in, (const float*)W,
                                    (const float*)bias, len, b, dir, seq_out, hfin);
  } else {
    lstm_body<__hip_bfloat16, XK, WRITE_SEQ>(x, (const __hip_bfloat16*)E, seq_in,
                                             (const __hip_bfloat16*)W, (const __hip_bfloat16*)bias,
                                             len, b, dir, seq_out, hfin);
  }
}

// ---------------------------------------------------------------------------
template <typename TW>
__device__ __forceinline__ void fc_body(const float* __restrict__ hfin, const TW* __restrict__ Wfc,
                                        const TW* __restrict__ bfc, TW* __restrict__ out) {
  const int idx = threadIdx.x;
  const int b = idx >> 1;
  const int cc = idx & 1;
  float acc = ldf(bfc, cc);
  for (int k = 0; k < Hn; ++k) acc += hfin[(0 * Bn + b) * Hn + k] * ldf(Wfc, k * 2 + cc);
  for (int k = 0; k < Hn; ++k) acc += hfin[(1 * Bn + b) * Hn + k] * ldf(Wfc, (Hn + k) * 2 + cc);
  if constexpr (sizeof(TW) == 2) {
    out[b * 2 + cc] = __float2bfloat16(acc);
  } else {
    out[b * 2 + cc] = acc;
  }
}

__global__ void k_fc(const float* __restrict__ hfin, const void* __restrict__ Wfc,
                     const void* __restrict__ bfc, const int* __restrict__ flag,
                     void* __restrict__ out) {
  if (flag[0]) {
    fc_body<float>(hfin, (const float*)Wfc, (const float*)bfc, (float*)out);
  } else {
    fc_body<__hip_bfloat16>(hfin, (const __hip_bfloat16*)Wfc, (const __hip_bfloat16*)bfc,
                            (__hip_bfloat16*)out);
  }
}

// ---------------------------------------------------------------------------
extern "C" void kernel_launch(void* const* d_in, const int* in_sizes, int n_in,
                              void* d_out, int out_size, void* d_ws, size_t ws_size,
                              hipStream_t stream) {
  const int* x = (const int*)d_in[0];
  const void* E = d_in[1];
  const void* Wf0 = d_in[2];
  const void* bf0 = d_in[3];
  const void* Wb0 = d_in[4];
  const void* bb0 = d_in[5];
  const void* Wf1 = d_in[6];
  const void* bf1 = d_in[7];
  const void* Wb1 = d_in[8];
  const void* bb1 = d_in[9];
  const void* Wfc = d_in[10];
  const void* bfc = d_in[11];

  char* ws = (char*)d_ws;
  int* flag = (int*)ws;             // @0
  int* lengths = (int*)(ws + 256);

  const size_t MB = 1ull << 20;
  const size_t KB = 1024;

  k_detect<<<1, 256, 0, stream>>>((const unsigned short*)E, flag);
  k_lengths<<<Bn, 256, 0, stream>>>(x, lengths);

  // pick largest xproj chunk (Tc timesteps/dir, Tc*0.5 MB) that fits ws
  int Tc = 0;
  {
    const size_t fixed = 73 * MB + MB;  // weights/state/mailbox/seq0 + slack
    const int cands[7] = {1024, 512, 256, 128, 64, 32, 16};
    for (int i = 0; i < 7; ++i)
      if (fixed + (size_t)cands[i] * 512 * KB <= ws_size) { Tc = cands[i]; break; }
  }

  if (Tc > 0) {
    float* biasbuf = (float*)(ws + 4096);                    // 16 KB
    __hip_bfloat16* whT = (__hip_bfloat16*)(ws + 1 * MB);    // [4][1024][256] = 2 MB
    __hip_bfloat16* wxT0 = (__hip_bfloat16*)(ws + 3 * MB);   // [2][1024][256] = 1 MB
    __hip_bfloat16* wxT1 = (__hip_bfloat16*)(ws + 4 * MB);   // [2][1024][512] = 2 MB
    unsigned* hgs0 = (unsigned*)(ws + 6 * MB);               // [2][2][4][4096] u32 = 256 KB
    unsigned* hgs1 = (unsigned*)(ws + 6 * MB + 256 * KB);    // 256 KB
    float* cstate0 = (float*)(ws + 7 * MB);                  // 128 KB
    float* hstate0 = (float*)(ws + 7 * MB + 128 * KB);       // 128 KB
    float* cstate1 = (float*)(ws + 7 * MB + 256 * KB);       // 128 KB
    float* hstate1 = (float*)(ws + 7 * MB + 384 * KB);       // 128 KB
    __hip_bfloat16* seq0 = (__hip_bfloat16*)(ws + 8 * MB);   // [1024][64][512] = 64 MB
    float* xproj = (float*)(ws + 73 * MB);                   // [2][Tc][64][1024] f32

    k_prep_small<<<1, 256, 0, stream>>>(bf0, bb0, bf1, bb1, flag, biasbuf);
    k_prepw<<<dim3(12, 16, 4), 256, 0, stream>>>(Wf0, Wb0, Wf1, Wb1, flag, whT, wxT0, wxT1);
    hipMemsetAsync(hgs0, 0, 512 * KB, stream);  // both mailboxes: kill stale tags

    const int P = Tn / Tc;
    // layer 0
    for (int p = 0; p < P; ++p) {
      const int s0 = p * Tc;
      const int t0f = s0, t0b = Tn - s0 - Tc;
      k_xproj<0><<<dim3(Tc, 16, 2), 256, 0, stream>>>(x, E, flag, nullptr, wxT0, biasbuf, xproj,
                                                      t0f, t0b, Tc);
      k_lstm_fast<true><<<8, 256, 0, stream>>>(whT, xproj, lengths, hgs0, cstate0, hstate0, seq0,
                                               s0, Tc);
    }
    // layer 1
    for (int p = 0; p < P; ++p) {
      const int s0 = p * Tc;
      const int t0f = s0, t0b = Tn - s0 - Tc;
      k_xproj<1><<<dim3(Tc, 16, 2), 256, 0, stream>>>(x, E, flag, seq0, wxT1, biasbuf + 2048,
                                                      xproj, t0f, t0b, Tc);
      k_lstm_fast<false><<<8, 256, 0, stream>>>(whT + 2 * 1024 * 256, xproj, lengths, hgs1,
                                                cstate1, hstate1, nullptr, s0, Tc);
    }
    k_fc<<<1, 128, 0, stream>>>(hstate1, Wfc, bfc, flag, d_out);
  } else {
    // slow fallback (round-2 passing path)
    __hip_bfloat16* seq0 = (__hip_bfloat16*)(ws + 64 * 1024);
    const size_t seq0_bytes = (size_t)Bn * Tn * 2 * Hn * sizeof(__hip_bfloat16);
    float* hfin = (float*)(ws + 64 * 1024 + seq0_bytes);
    k_lstm<Dn, true><<<2 * Bn, 256, 0, stream>>>(x, E, nullptr, Wf0, bf0, Wb0, bb0, lengths, flag,
                                                 seq0, nullptr);
    k_lstm<2 * Hn, false><<<2 * Bn, 256, 0, stream>>>(x, E, seq0, Wf1, bf1, Wb1, bb1, lengths,
                                                      flag, nullptr, hfin);
    k_fc<<<1, 128, 0, stream>>>(hfin, Wfc, bfc, flag, d_out);
  }
}

// Round 9
// 15275.513 us; speedup vs baseline: 1.5736x; 1.2526x over previous
//
#include <hip/hip_runtime.h>
#include <hip/hip_bf16.h>
#include <math.h>

// Problem constants: V=32000, D=256, H=256, L=2, C=2, B=64, T=1024, PAD=0
namespace {
constexpr int Bn = 64;
constexpr int Tn = 1024;
constexpr int Dn = 256;
constexpr int Hn = 256;
}

typedef __attribute__((ext_vector_type(8))) short short8;
typedef __attribute__((ext_vector_type(4))) float f32x4;

template <typename T>
__device__ __forceinline__ float ldf(const T* p, long i);
template <>
__device__ __forceinline__ float ldf<float>(const float* p, long i) { return p[i]; }
template <>
__device__ __forceinline__ float ldf<__hip_bfloat16>(const __hip_bfloat16* p, long i) {
  return __bfloat162float(p[i]);
}

__device__ __forceinline__ float sigmf(float x) { return 1.0f / (1.0f + __expf(-x)); }
__device__ __forceinline__ float tanh_fast(float x) {
  return 1.0f - 2.0f / (__expf(2.0f * x) + 1.0f);
}

// ---------------------------------------------------------------------------
// Dtype detector (validated round 2: flag=1 -> f32 inputs).
// ---------------------------------------------------------------------------
__global__ void k_detect(const unsigned short* __restrict__ e, int* __restrict__ flag) {
  __shared__ int sbuf[256];
  int bad = 0;
  for (int i = threadIdx.x; i < 4096; i += 256) {
    const unsigned short v = e[i];
    const int ex = (v >> 7) & 0xFF;
    bad += (ex >= 137) ? 1 : 0;
  }
  sbuf[threadIdx.x] = bad;
  __syncthreads();
  for (int s = 128; s > 0; s >>= 1) {
    if (threadIdx.x < s) sbuf[threadIdx.x] += sbuf[threadIdx.x + s];
    __syncthreads();
  }
  if (threadIdx.x == 0) flag[0] = (sbuf[0] > 64) ? 1 : 0;
}

__global__ void k_lengths(const int* __restrict__ x, int* __restrict__ len) {
  const int b = blockIdx.x;
  int cnt = 0;
  for (int t = threadIdx.x; t < Tn; t += blockDim.x) cnt += (x[b * Tn + t] != 0) ? 1 : 0;
  __shared__ int sbuf[256];
  sbuf[threadIdx.x] = cnt;
  __syncthreads();
  for (int s = 128; s > 0; s >>= 1) {
    if (threadIdx.x < s) sbuf[threadIdx.x] += sbuf[threadIdx.x + s];
    __syncthreads();
  }
  if (threadIdx.x == 0) len[b] = sbuf[0];
}

// ===========================================================================
// FAST PATH
// ===========================================================================

// biases -> f32 [4][1024] (order: f0,b0,f1,b1).
__global__ void k_prep_small(const void* b0f, const void* b0b, const void* b1f, const void* b1b,
                             const int* __restrict__ flag, float* __restrict__ biasbuf) {
  const int tid = threadIdx.x;
  const bool isf32 = flag[0] != 0;
  for (int idx = tid; idx < 4096; idx += 256) {
    const int j = idx >> 10, col = idx & 1023;
    const void* src = (j == 0) ? b0f : (j == 1) ? b0b : (j == 2) ? b1f : b1b;
    biasbuf[idx] = isf32 ? ((const float*)src)[col]
                         : __bfloat162float(((const __hip_bfloat16*)src)[col]);
  }
}

// Transpose+convert W[(H+XK) x 1024] -> WhT bf16 [1024][256], WxT bf16 [1024][XK].
__global__ void k_prepw(const void* W0, const void* W1, const void* W2, const void* W3,
                        const int* __restrict__ flag, __hip_bfloat16* __restrict__ whT,
                        __hip_bfloat16* __restrict__ wxT0, __hip_bfloat16* __restrict__ wxT1) {
  const int j = blockIdx.z;
  const int rows = (j < 2) ? 512 : 768;
  const int bx = blockIdx.x;
  if (bx * 64 >= rows) return;
  const int by = blockIdx.y;
  const void* W = (j == 0) ? W0 : (j == 1) ? W1 : (j == 2) ? W2 : W3;
  const bool isf32 = flag[0] != 0;
  __shared__ float tile[64][65];
  const int tid = threadIdx.x;
  const int c = tid & 63, r4 = tid >> 6;
#pragma unroll
  for (int rep = 0; rep < 16; ++rep) {
    const int rr = r4 * 16 + rep;
    const size_t idx = (size_t)(bx * 64 + rr) * 1024 + by * 64 + c;
    tile[rr][c] = isf32 ? ((const float*)W)[idx]
                        : __bfloat162float(((const __hip_bfloat16*)W)[idx]);
  }
  __syncthreads();
  const int kk = tid & 63;
#pragma unroll
  for (int rep = 0; rep < 16; ++rep) {
    const int a = r4 * 16 + rep;
    const int n = by * 64 + a;
    const int k = bx * 64 + kk;
    const __hip_bfloat16 v = __float2bfloat16(tile[kk][a]);
    if (k < 256) {
      whT[(size_t)j * (1024 * 256) + (size_t)n * 256 + k] = v;
    } else {
      const int k2 = k - 256;
      if (j < 2)
        wxT0[(size_t)j * (1024 * 256) + (size_t)n * 256 + k2] = v;
      else
        wxT1[(size_t)(j - 2) * (1024 * 512) + (size_t)n * 512 + k2] = v;
    }
  }
}

// ---------------------------------------------------------------------------
// Per-phase embedding gather -> xemb[d][tl*64+b][256] bf16 (contiguous A rows).
// ---------------------------------------------------------------------------
__global__ void k_gather2(const int* __restrict__ x, const void* __restrict__ E,
                          const int* __restrict__ flag, __hip_bfloat16* __restrict__ xemb,
                          const int t0f, const int t0b, const int Tc) {
  const int d = blockIdx.y, tl = blockIdx.x, tid = threadIdx.x;
  const int t = (d ? t0b : t0f) + tl;
  __hip_bfloat16* __restrict__ dst = xemb + ((size_t)(d * Tc + tl) * 64) * 256;
  const bool isf32 = flag[0] != 0;
  for (int b = 0; b < 64; ++b) {
    const int tok = x[b * Tn + t];
    const float v = isf32 ? ((const float*)E)[(size_t)tok * Dn + tid]
                          : __bfloat162float(((const __hip_bfloat16*)E)[(size_t)tok * Dn + tid]);
    dst[b * 256 + tid] = __float2bfloat16(v);
  }
}

// ---------------------------------------------------------------------------
// Tiled xproj GEMM: out[d][Mrows][1024] f32 = A_d[Mrows][K] @ WT_d^T + bias_d.
// 128x128 tile/block; B-tile (128 cols x 256 k) staged in LDS (pad +8 shorts:
// col stride 528 B -> 2-way bank alias, free), reused by all 4 waves; K=512
// loops two 256-k chunks. Wave w: rows [w*32, w*32+32) (2 m-tiles), 8 n-tiles.
// grid (Mrows/128, 8, 2). A rows are contiguous per direction.
// ---------------------------------------------------------------------------
template <int K>
__launch_bounds__(256, 2)
__global__ void k_xproj2(const __hip_bfloat16* __restrict__ Af,
                         const __hip_bfloat16* __restrict__ Ab,
                         const __hip_bfloat16* __restrict__ WT,  // [2][1024][K]
                         const float* __restrict__ bias,         // [2][1024]
                         float* __restrict__ xp,                 // [2][Mrows][1024]
                         const int Mrows) {
  constexpr int KC = 256;
  constexpr int NCH = K / KC;
  __shared__ __hip_bfloat16 Btile[128][KC + 8];
  const int bx = blockIdx.x, by = blockIdx.y, dz = blockIdx.z;
  const int tid = threadIdx.x, w = tid >> 6, L = tid & 63, quad = L >> 4, l16 = L & 15;
  const __hip_bfloat16* __restrict__ A = dz ? Ab : Af;
  const __hip_bfloat16* __restrict__ WTd = WT + (size_t)dz * (1024 * K);
  float* __restrict__ o = xp + (size_t)dz * Mrows * 1024;

  f32x4 acc[2][8];
#pragma unroll
  for (int nt = 0; nt < 8; ++nt) {
    const float bv = bias[dz * 1024 + by * 128 + nt * 16 + l16];
#pragma unroll
    for (int mt = 0; mt < 2; ++mt) {
      acc[mt][nt][0] = bv; acc[mt][nt][1] = bv; acc[mt][nt][2] = bv; acc[mt][nt][3] = bv;
    }
  }

  const __hip_bfloat16* __restrict__ arow0 = A + (size_t)(bx * 128 + w * 32 + l16) * K;

  for (int ch = 0; ch < NCH; ++ch) {
    if (ch) __syncthreads();
    // stage B chunk: 128 cols x 256 shorts (flat copy, 16 iters x 16 B/thread)
#pragma unroll
    for (int it = 0; it < 16; ++it) {
      const int idx = it * 256 + tid;      // 0..4095
      const int col = idx >> 5, seg = idx & 31;
      *(short8*)&Btile[col][seg * 8] =
          *(const short8*)(WTd + (size_t)(by * 128 + col) * K + ch * KC + seg * 8);
    }
    __syncthreads();

#pragma unroll
    for (int kc = 0; kc < 8; ++kc) {
      const short8 a0 = *(const short8*)(arow0 + ch * KC + kc * 32 + quad * 8);
      const short8 a1 = *(const short8*)(arow0 + 16 * K + ch * KC + kc * 32 + quad * 8);
#pragma unroll
      for (int nt = 0; nt < 8; ++nt) {
        const short8 b = *(const short8*)&Btile[nt * 16 + l16][kc * 32 + quad * 8];
        acc[0][nt] = __builtin_amdgcn_mfma_f32_16x16x32_bf16(a0, b, acc[0][nt], 0, 0, 0);
        acc[1][nt] = __builtin_amdgcn_mfma_f32_16x16x32_bf16(a1, b, acc[1][nt], 0, 0, 0);
      }
    }
  }

#pragma unroll
  for (int mt = 0; mt < 2; ++mt)
#pragma unroll
    for (int nt = 0; nt < 8; ++nt)
#pragma unroll
      for (int r = 0; r < 4; ++r)
        o[(size_t)(bx * 128 + w * 32 + mt * 16 + quad * 4 + r) * 1024 + by * 128 + nt * 16 +
          l16] = acc[mt][nt][r];
}

// ---------------------------------------------------------------------------
// Phased recurrent layer, TAGGED-PAYLOAD sync (round-8, validated; + s_sleep
// backoff on retry). 8 blocks: blockIdx.x = d*4+q.
// ---------------------------------------------------------------------------
template <bool WRITE_SEQ>
__launch_bounds__(256, 1) __global__
void k_lstm_fast(const __hip_bfloat16* __restrict__ WhT,  // [2][1024][256] this layer
                 const float* __restrict__ xproj,          // [2][Tc][64][1024] f32
                 const int* __restrict__ lengths,
                 unsigned* __restrict__ hgs,  // [2 d][2 par][4 q][64 b][64 u] u32
                 float* __restrict__ cstate, float* __restrict__ hstate,  // [2][64][256]
                 __hip_bfloat16* __restrict__ seq0,        // [T][64][512]
                 const int s0, const int Tc) {
  const int d = blockIdx.x >> 2;
  const int q = blockIdx.x & 3;
  const int tid = threadIdx.x;
  const int w = tid >> 6, L = tid & 63, quad = L >> 4, l16 = L & 15;
  const int u = q * 64 + w * 16 + l16;

  __shared__ __hip_bfloat16 h_lds[64][272];
  for (int idx = tid; idx < 64 * 272; idx += 256) (&h_lds[0][0])[idx] = __float2bfloat16(0.0f);

  const __hip_bfloat16* __restrict__ Wd = WhT + (size_t)d * (1024 * 256);
  short8 wfrag[4][8];
#pragma unroll
  for (int g = 0; g < 4; ++g)
#pragma unroll
    for (int kc = 0; kc < 8; ++kc)
      wfrag[g][kc] = *(const short8*)(Wd + (size_t)(g * 256 + u) * 256 + kc * 32 + quad * 8);

  float c_reg[16], h_reg[16];
  int len_b[16];
#pragma unroll
  for (int mt = 0; mt < 4; ++mt)
#pragma unroll
    for (int r = 0; r < 4; ++r) {
      const int idx = mt * 4 + r;
      const int b = mt * 16 + quad * 4 + r;
      len_b[idx] = lengths[b];
      if (s0 == 0) {
        c_reg[idx] = 0.0f;
        h_reg[idx] = 0.0f;
      } else {
        c_reg[idx] = cstate[((size_t)(d * 64 + b) << 8) + u];
        h_reg[idx] = hstate[((size_t)(d * 64 + b) << 8) + u];
      }
    }
  __syncthreads();
#pragma unroll
  for (int mt = 0; mt < 4; ++mt)
#pragma unroll
    for (int r = 0; r < 4; ++r)
      h_lds[mt * 16 + quad * 4 + r][u] = __float2bfloat16(h_reg[mt * 4 + r]);
  __syncthreads();

  for (int sl = 0; sl < Tc; ++sl) {
    const int s = s0 + sl;
    const int t = d ? (Tn - 1 - s) : s;
    const int tl = d ? (Tc - 1 - sl) : sl;

    // 1. C-init from xproj
    f32x4 acc[4][4];
#pragma unroll
    for (int mt = 0; mt < 4; ++mt) {
      const float* __restrict__ xrow =
          xproj + ((size_t)(d * Tc + tl) * 64 + mt * 16 + quad * 4) * 1024 + u;
#pragma unroll
      for (int g = 0; g < 4; ++g)
#pragma unroll
        for (int r = 0; r < 4; ++r) acc[mt][g][r] = xrow[(size_t)r * 1024 + g * 256];
    }

    // 2. tagged-payload exchange (single RT in the common case)
    if (s > 0) {
      if (w != q) {
        const unsigned long long* __restrict__ src64 =
            (const unsigned long long*)(hgs + ((((size_t)d * 2 + ((s - 1) & 1)) * 4 + w) << 12));
        const unsigned exp = (unsigned)s;
        unsigned long long v[32];
        unsigned pend = 0xFFFFFFFFu;
        int tries = 0;
        do {
          if (tries++) __builtin_amdgcn_s_sleep(1);
#pragma unroll
          for (int i = 0; i < 32; ++i)
            if (pend & (1u << i))
              v[i] = __hip_atomic_load(src64 + i * 64 + L, __ATOMIC_RELAXED,
                                       __HIP_MEMORY_SCOPE_AGENT);
#pragma unroll
          for (int i = 0; i < 32; ++i)
            if (pend & (1u << i)) {
              const unsigned lo = (unsigned)v[i], hi = (unsigned)(v[i] >> 32);
              if ((lo >> 16) == exp && (hi >> 16) == exp) pend &= ~(1u << i);
            }
        } while (pend);
#pragma unroll
        for (int i = 0; i < 32; ++i) {
          const int j = i * 64 + L;
          const unsigned lo = (unsigned)v[i], hi = (unsigned)(v[i] >> 32);
          const unsigned packed = (lo & 0xFFFFu) | (hi << 16);
          *(unsigned*)&h_lds[j >> 5][w * 64 + (j & 31) * 2] = packed;
        }
      }
      __syncthreads();
    }

    // 3. z += h @ Wh
#pragma unroll
    for (int kc = 0; kc < 8; ++kc) {
#pragma unroll
      for (int mt = 0; mt < 4; ++mt) {
        const short8 a = *(const short8*)&h_lds[mt * 16 + l16][kc * 32 + quad * 8];
#pragma unroll
        for (int g = 0; g < 4; ++g)
          acc[mt][g] =
              __builtin_amdgcn_mfma_f32_16x16x32_bf16(a, wfrag[g][kc], acc[mt][g], 0, 0, 0);
      }
    }

    // 4. gates + state update; publish tagged slice (write-through u32)
    unsigned* __restrict__ dst32 = hgs + ((((size_t)d * 2 + (s & 1)) * 4 + q) << 12);
    const unsigned tag = ((unsigned)(s + 1)) << 16;
    __hip_bfloat16 hbf[16];
#pragma unroll
    for (int mt = 0; mt < 4; ++mt)
#pragma unroll
      for (int r = 0; r < 4; ++r) {
        const int idx = mt * 4 + r, b = mt * 16 + quad * 4 + r;
        const float fg = sigmf(acc[mt][0][r]);
        const float ig = sigmf(acc[mt][1][r]);
        const float gg = tanh_fast(acc[mt][2][r]);
        const float og = sigmf(acc[mt][3][r]);
        const float cn = fg * c_reg[idx] + ig * gg;
        const float hn = og * tanh_fast(cn);
        if (t < len_b[idx]) {
          c_reg[idx] = cn;
          h_reg[idx] = hn;
        }
        hbf[idx] = __float2bfloat16(h_reg[idx]);
        __hip_atomic_store(dst32 + b * 64 + w * 16 + l16,
                           tag | (unsigned)*(unsigned short*)&hbf[idx], __ATOMIC_RELAXED,
                           __HIP_MEMORY_SCOPE_AGENT);
      }

    __syncthreads();  // LDS overwrite guard

#pragma unroll
    for (int mt = 0; mt < 4; ++mt)
#pragma unroll
      for (int r = 0; r < 4; ++r)
        h_lds[mt * 16 + quad * 4 + r][u] = hbf[mt * 4 + r];

    if (WRITE_SEQ) {
#pragma unroll
      for (int mt = 0; mt < 4; ++mt)
#pragma unroll
        for (int r = 0; r < 4; ++r) {
          const int b = mt * 16 + quad * 4 + r;
          seq0[((size_t)t * 64 + b) * 512 + d * 256 + u] = hbf[mt * 4 + r];
        }
    }
  }

#pragma unroll
  for (int mt = 0; mt < 4; ++mt)
#pragma unroll
    for (int r = 0; r < 4; ++r) {
      const int idx = mt * 4 + r, b = mt * 16 + quad * 4 + r;
      cstate[((size_t)(d * 64 + b) << 8) + u] = c_reg[idx];
      hstate[((size_t)(d * 64 + b) << 8) + u] = h_reg[idx];
    }
}

// ===========================================================================
// SLOW FALLBACK PATH (round-2 passing version, used when ws is too small)
// ===========================================================================
template <typename TW, int XK, bool WRITE_SEQ>
__device__ __forceinline__ void lstm_body(const int* __restrict__ x, const TW* __restrict__ E,
                                          const __hip_bfloat16* __restrict__ seq_in,
                                          const TW* __restrict__ W, const TW* __restrict__ bias,
                                          const int len, const int b, const int dir,
                                          __hip_bfloat16* __restrict__ seq_out,
                                          float* __restrict__ hfin) {
  const int j = threadIdx.x;
  __shared__ float h[Hn];
  __shared__ float xb[XK];
  float hj = 0.0f, cj = 0.0f;
  h[j] = 0.0f;
  const float bfj = ldf(bias, j);
  const float bij = ldf(bias, Hn + j);
  const float bgj = ldf(bias, 2 * Hn + j);
  const float boj = ldf(bias, 3 * Hn + j);
  __syncthreads();
  for (int s = 0; s < Tn; ++s) {
    const int t = dir ? (Tn - 1 - s) : s;
    const bool active = (t < len);
    if (active) {
      if constexpr (XK == Dn) {
        const int tok = x[b * Tn + t];
        xb[j] = ldf(E, (long)tok * Dn + j);
      } else {
        const long base = ((long)(b * Tn + t)) * (2 * Hn);
        xb[j] = __bfloat162float(seq_in[base + j]);
        xb[j + Hn] = __bfloat162float(seq_in[base + j + Hn]);
      }
      __syncthreads();
      float af = bfj, ai = bij, ag = bgj, ao = boj;
#pragma unroll 4
      for (int k = 0; k < Hn; ++k) {
        const float hk = h[k];
        const long r = (long)k * (4 * Hn);
        af += hk * ldf(W, r + j);
        ai += hk * ldf(W, r + Hn + j);
        ag += hk * ldf(W, r + 2 * Hn + j);
        ao += hk * ldf(W, r + 3 * Hn + j);
      }
#pragma unroll 4
      for (int k = 0; k < XK; ++k) {
        const float xk = xb[k];
        const long r = (long)(Hn + k) * (4 * Hn);
        af += xk * ldf(W, r + j);
        ai += xk * ldf(W, r + Hn + j);
        ag += xk * ldf(W, r + 2 * Hn + j);
        ao += xk * ldf(W, r + 3 * Hn + j);
      }
      const float fg = 1.0f / (1.0f + expf(-af));
      const float ig = 1.0f / (1.0f + expf(-ai));
      const float gg = tanhf(ag);
      const float og = 1.0f / (1.0f + expf(-ao));
      const float cn = fg * cj + ig * gg;
      const float hn = og * tanhf(cn);
      __syncthreads();
      hj = hn;
      cj = cn;
      h[j] = hn;
      __syncthreads();
    }
    if constexpr (WRITE_SEQ) {
      seq_out[((long)(b * Tn + t)) * (2 * Hn) + dir * Hn + j] = __float2bfloat16(hj);
    }
  }
  if constexpr (!WRITE_SEQ) hfin[(dir * Bn + b) * Hn + j] = hj;
}

template <int XK, bool WRITE_SEQ>
__global__ void k_lstm(const int* __restrict__ x, const void* __restrict__ E,
                       const __hip_bfloat16* __restrict__ seq_in, const void* __restrict__ Wf,
                       const void* __restrict__ bf, const void* __restrict__ Wb,
                       const void* __restrict__ bb, const int* __restrict__ lengths,
                       const int* __restrict__ flag, __hip_bfloat16* __restrict__ seq_out,
                       float* __restrict__ hfin) {
  const int b = blockIdx.x & (Bn - 1);
  const int dir = blockIdx.x >> 6;
  const int len = lengths[b];
  const void* W = dir ? Wb : Wf;
  const void* bias = dir ? bb : bf;
  if (flag[0]) {
    lstm_body<float, XK, WRITE_SEQ>(x, (const float*)E, seq_in, (const float*)W,
                                    (const float*)bias, len, b, dir, seq_out, hfin);
  } else {
    lstm_body<__hip_bfloat16, XK, WRITE_SEQ>(x, (const __hip_bfloat16*)E, seq_in,
                                             (const __hip_bfloat16*)W, (const __hip_bfloat16*)bias,
                                             len, b, dir, seq_out, hfin);
  }
}

// ---------------------------------------------------------------------------
template <typename TW>
__device__ __forceinline__ void fc_body(const float* __restrict__ hfin, const TW* __restrict__ Wfc,
                                        const TW* __restrict__ bfc, TW* __restrict__ out) {
  const int idx = threadIdx.x;
  const int b = idx >> 1;
  const int cc = idx & 1;
  float acc = ldf(bfc, cc);
  for (int k = 0; k < Hn; ++k) acc += hfin[(0 * Bn + b) * Hn + k] * ldf(Wfc, k * 2 + cc);
  for (int k = 0; k < Hn; ++k) acc += hfin[(1 * Bn + b) * Hn + k] * ldf(Wfc, (Hn + k) * 2 + cc);
  if constexpr (sizeof(TW) == 2) {
    out[b * 2 + cc] = __float2bfloat16(acc);
  } else {
    out[b * 2 + cc] = acc;
  }
}

__global__ void k_fc(const float* __restrict__ hfin, const void* __restrict__ Wfc,
                     const void* __restrict__ bfc, const int* __restrict__ flag,
                     void* __restrict__ out) {
  if (flag[0]) {
    fc_body<float>(hfin, (const float*)Wfc, (const float*)bfc, (float*)out);
  } else {
    fc_body<__hip_bfloat16>(hfin, (const __hip_bfloat16*)Wfc, (const __hip_bfloat16*)bfc,
                            (__hip_bfloat16*)out);
  }
}

// ---------------------------------------------------------------------------
extern "C" void kernel_launch(void* const* d_in, const int* in_sizes, int n_in,
                              void* d_out, int out_size, void* d_ws, size_t ws_size,
                              hipStream_t stream) {
  const int* x = (const int*)d_in[0];
  const void* E = d_in[1];
  const void* Wf0 = d_in[2];
  const void* bf0 = d_in[3];
  const void* Wb0 = d_in[4];
  const void* bb0 = d_in[5];
  const void* Wf1 = d_in[6];
  const void* bf1 = d_in[7];
  const void* Wb1 = d_in[8];
  const void* bb1 = d_in[9];
  const void* Wfc = d_in[10];
  const void* bfc = d_in[11];

  char* ws = (char*)d_ws;
  int* flag = (int*)ws;             // @0
  int* lengths = (int*)(ws + 256);

  const size_t MB = 1ull << 20;
  const size_t KB = 1024;

  k_detect<<<1, 256, 0, stream>>>((const unsigned short*)E, flag);
  k_lengths<<<Bn, 256, 0, stream>>>(x, lengths);

  // per-Tc scratch: xemb (Tc*64 KB) + xproj (Tc*512 KB) = Tc*576 KB
  int Tc = 0;
  {
    const size_t fixed = 73 * MB;
    const int cands[7] = {1024, 512, 256, 128, 64, 32, 16};
    for (int i = 0; i < 7; ++i)
      if (fixed + (size_t)cands[i] * 576 * KB <= ws_size) { Tc = cands[i]; break; }
  }

  if (Tc > 0) {
    float* biasbuf = (float*)(ws + 4096);                    // 16 KB
    __hip_bfloat16* whT = (__hip_bfloat16*)(ws + 1 * MB);    // [4][1024][256] = 2 MB
    __hip_bfloat16* wxT0 = (__hip_bfloat16*)(ws + 3 * MB);   // [2][1024][256] = 1 MB
    __hip_bfloat16* wxT1 = (__hip_bfloat16*)(ws + 4 * MB);   // [2][1024][512] = 2 MB
    unsigned* hgs0 = (unsigned*)(ws + 6 * MB);               // 256 KB
    unsigned* hgs1 = (unsigned*)(ws + 6 * MB + 256 * KB);    // 256 KB
    float* cstate0 = (float*)(ws + 7 * MB);                  // 128 KB
    float* hstate0 = (float*)(ws + 7 * MB + 128 * KB);       // 128 KB
    float* cstate1 = (float*)(ws + 7 * MB + 256 * KB);       // 128 KB
    float* hstate1 = (float*)(ws + 7 * MB + 384 * KB);       // 128 KB
    __hip_bfloat16* seq0 = (__hip_bfloat16*)(ws + 8 * MB);   // [1024][64][512] = 64 MB
    __hip_bfloat16* xemb = (__hip_bfloat16*)(ws + 73 * MB);  // [2][Tc*64][256] = Tc*64 KB
    float* xproj = (float*)(ws + 73 * MB + (size_t)Tc * 64 * KB);  // [2][Tc*64][1024] f32

    k_prep_small<<<1, 256, 0, stream>>>(bf0, bb0, bf1, bb1, flag, biasbuf);
    k_prepw<<<dim3(12, 16, 4), 256, 0, stream>>>(Wf0, Wb0, Wf1, Wb1, flag, whT, wxT0, wxT1);
    hipMemsetAsync(hgs0, 0, 512 * KB, stream);  // both mailboxes: kill stale tags

    const int P = Tn / Tc;
    const int Mrows = Tc * 64;
    // layer 0
    for (int p = 0; p < P; ++p) {
      const int s0 = p * Tc;
      const int t0f = s0, t0b = Tn - s0 - Tc;
      k_gather2<<<dim3(Tc, 2), 256, 0, stream>>>(x, E, flag, xemb, t0f, t0b, Tc);
      k_xproj2<256><<<dim3(Tc / 2, 8, 2), 256, 0, stream>>>(
          xemb, xemb + (size_t)Mrows * 256, wxT0, biasbuf, xproj, Mrows);
      k_lstm_fast<true><<<8, 256, 0, stream>>>(whT, xproj, lengths, hgs0, cstate0, hstate0, seq0,
                                               s0, Tc);
    }
    // layer 1
    for (int p = 0; p < P; ++p) {
      const int s0 = p * Tc;
      const int t0f = s0, t0b = Tn - s0 - Tc;
      k_xproj2<512><<<dim3(Tc / 2, 8, 2), 256, 0, stream>>>(
          seq0 + (size_t)t0f * 64 * 512, seq0 + (size_t)t0b * 64 * 512, wxT1, biasbuf + 2048,
          xproj, Mrows);
      k_lstm_fast<false><<<8, 256, 0, stream>>>(whT + 2 * 1024 * 256, xproj, lengths, hgs1,
                                                cstate1, hstate1, nullptr, s0, Tc);
    }
    k_fc<<<1, 128, 0, stream>>>(hstate1, Wfc, bfc, flag, d_out);
  } else {
    // slow fallback (round-2 passing path)
    __hip_bfloat16* seq0 = (__hip_bfloat16*)(ws + 64 * 1024);
    const size_t seq0_bytes = (size_t)Bn * Tn * 2 * Hn * sizeof(__hip_bfloat16);
    float* hfin = (float*)(ws + 64 * 1024 + seq0_bytes);
    k_lstm<Dn, true><<<2 * Bn, 256, 0, stream>>>(x, E, nullptr, Wf0, bf0, Wb0, bb0, lengths, flag,
                                                 seq0, nullptr);
    k_lstm<2 * Hn, false><<<2 * Bn, 256, 0, stream>>>(x, E, seq0, Wf1, bf1, Wb1, bb1, lengths,
                                                      flag, nullptr, hfin);
    k_fc<<<1, 128, 0, stream>>>(hfin, Wfc, bfc, flag, d_out);
  }
}